// Round 1
// baseline (195.638 us; speedup 1.0000x reference)
//
#include <hip/hip_runtime.h>

// Problem constants (from reference)
#define N_CAM   6
#define N_REF   4
#define N_HEADS 8
#define EMBD    256
#define HS      32
#define L       100     // seq_len = 10*10
#define BS      2
#define CAM_STRIDE (L * EMBD)   // 25600 floats per (b, cam)

// ---------------------------------------------------------------------------
// Kernel 1: fold W_v (1536 x 1024) over the 4 ref slots -> W_sum (1536 x 256)
// W_sum[i][e] = sum_ref W_v[i][ref*256 + e]
// float4-vectorized: 1536 rows x 64 float4 cols = 98304 threads.
// ---------------------------------------------------------------------------
__global__ __launch_bounds__(256) void wsum_kernel(const float4* __restrict__ Wv4,
                                                   float4* __restrict__ wsum4) {
    int tid = blockIdx.x * 256 + threadIdx.x;      // 0 .. 1536*64-1
    int i  = tid >> 6;                             // row in [0,1536)
    int e4 = tid & 63;                             // float4 col in [0,64)
    // W_v row i has 256 float4s; ref slot r occupies float4s [r*64, r*64+64)
    const float4* row = Wv4 + (size_t)i * 256;
    float4 a = row[e4];
    float4 b = row[64 + e4];
    float4 c = row[128 + e4];
    float4 d = row[192 + e4];
    float4 o;
    o.x = a.x + b.x + c.x + d.x;
    o.y = a.y + b.y + c.y + d.y;
    o.z = a.z + b.z + c.z + d.z;
    o.w = a.w + b.w + c.w + d.w;
    wsum4[(size_t)i * 64 + e4] = o;
}

// ---------------------------------------------------------------------------
// Kernel 2: Vsum[b][s][e] = sum_{cam,e2} feat[b,cam,s,e2] * W_sum[cam*256+e2][e]
//           + sum_ref b_v[ref*256+e]
// GEMM M=200 (rows = b*100+s), K=1536 (cam*256+e2), N=256 (e).
// One block = 8 rows x 256 cols; K staged one camera (256) at a time via LDS.
// ---------------------------------------------------------------------------
__global__ __launch_bounds__(256) void vsum_gemm_kernel(const float* __restrict__ feat,
                                                        const float* __restrict__ wsum,
                                                        const float* __restrict__ b_v,
                                                        float* __restrict__ vsum) {
    __shared__ float a_tile[8][256];
    const int t  = threadIdx.x;          // output column e
    const int r0 = blockIdx.x * 8;       // first row of this block's tile

    float acc[8];
#pragma unroll
    for (int j = 0; j < 8; ++j) acc[j] = 0.f;

    for (int cam = 0; cam < N_CAM; ++cam) {
        // stage A tile: a_tile[j][t] = v_in[r0+j][cam*256 + t]
#pragma unroll
        for (int j = 0; j < 8; ++j) {
            int row = r0 + j;
            int b = row / 100;
            int s = row - b * 100;
            a_tile[j][t] = feat[(size_t)(b * N_CAM + cam) * CAM_STRIDE + s * EMBD + t];
        }
        __syncthreads();

        const float* wcol = wsum + (size_t)cam * 256 * 256 + t;  // wsum[(cam*256+kk)*256 + t]
#pragma unroll 4
        for (int kk = 0; kk < 256; ++kk) {
            float w = wcol[kk * 256];
#pragma unroll
            for (int j = 0; j < 8; ++j) acc[j] += a_tile[j][kk] * w;
        }
        __syncthreads();
    }

    // bias fold (b_v is zeros in setup, but keep it correct)
    float bs_ = b_v[t] + b_v[256 + t] + b_v[512 + t] + b_v[768 + t];
#pragma unroll
    for (int j = 0; j < 8; ++j) {
        int row = r0 + j;
        vsum[(size_t)row * 256 + t] = acc[j] + bs_;
    }
}

// ---------------------------------------------------------------------------
// Kernel 3: fused scores + softmax-fold + weighted sum.
// One block per (b, sq); 256 threads.
//   E[h][sk]  = sum_cam exp( dot(q[b,sq,h,:], feat[b,cam,sk,h,:]) / sqrt(32) )
//   out[b,sq,h*32+d] = sum_sk E[h][sk]*Vsum[b,sk,h*32+d] / (4 * sum_sk E[h][sk])
// ---------------------------------------------------------------------------
__global__ __launch_bounds__(256) void attn_kernel(const float* __restrict__ feat,
                                                   const float* __restrict__ query,
                                                   const float* __restrict__ vsum,
                                                   float* __restrict__ out) {
    __shared__ float q_s[256];
    __shared__ float E_s[N_HEADS * L];     // [h*100 + sk]
    __shared__ float sumE_s[N_HEADS];

    const int t  = threadIdx.x;
    const int b  = blockIdx.x / 100;
    const int sq = blockIdx.x - b * 100;

    q_s[t] = query[(size_t)(b * L + sq) * EMBD + t];
    __syncthreads();

    const float scale = 0.17677669529663687f;  // 1/sqrt(32)
    const float* featb = feat + (size_t)b * N_CAM * CAM_STRIDE;

    // 800 (sk, h) pairs, p = sk*8 + h  ->  wave-coalesced feat reads
    for (int p = t; p < L * N_HEADS; p += 256) {
        int sk = p >> 3;
        int h  = p & 7;
        const float4* q4 = reinterpret_cast<const float4*>(&q_s[h * HS]);
        float e = 0.f;
        for (int cam = 0; cam < N_CAM; ++cam) {
            const float4* k4 = reinterpret_cast<const float4*>(
                featb + (size_t)cam * CAM_STRIDE + sk * EMBD + h * HS);
            float dot = 0.f;
#pragma unroll
            for (int i = 0; i < 8; ++i) {
                float4 qv = q4[i];
                float4 kv = k4[i];
                dot += qv.x * kv.x + qv.y * kv.y + qv.z * kv.z + qv.w * kv.w;
            }
            e += expf(dot * scale);
        }
        E_s[h * L + sk] = e;
    }
    __syncthreads();

    // parallel per-head sum of E: t = h*32 + lane
    {
        int h    = t >> 5;
        int lane = t & 31;
        float partial = E_s[h * L + lane] + E_s[h * L + lane + 32] + E_s[h * L + lane + 64];
        if (lane < 4) partial += E_s[h * L + lane + 96];
#pragma unroll
        for (int off = 16; off >= 1; off >>= 1)
            partial += __shfl_down(partial, off, 32);
        if (lane == 0) sumE_s[h] = partial;
    }
    __syncthreads();

    // weighted sum over sk
    const int h = t >> 5;
    const float* Eh = &E_s[h * L];
    const float* vb = vsum + (size_t)b * L * EMBD + t;
    float acc = 0.f;
#pragma unroll 4
    for (int sk = 0; sk < L; ++sk)
        acc += Eh[sk] * vb[sk * EMBD];

    out[(size_t)(b * L + sq) * EMBD + t] = acc * (0.25f / sumE_s[h]);
}

// ---------------------------------------------------------------------------
extern "C" void kernel_launch(void* const* d_in, const int* in_sizes, int n_in,
                              void* d_out, int out_size, void* d_ws, size_t ws_size,
                              hipStream_t stream) {
    const float* feat  = (const float*)d_in[0];  // (2,1,6,256,10,10) = (b,cam) x 25600
    const float* query = (const float*)d_in[1];  // (2,100,256)
    const float* Wv    = (const float*)d_in[2];  // (1536,1024)
    const float* bv    = (const float*)d_in[3];  // (1024,)
    float* outp = (float*)d_out;                 // (2,100,256)

    // workspace: W_sum (1536*256 f32) | Vsum (200*256 f32)
    float* wsum = (float*)d_ws;
    float* vsum = wsum + 1536 * 256;

    // K1: fold W_v columns -> W_sum
    wsum_kernel<<<1536 * 64 / 256, 256, 0, stream>>>(
        (const float4*)Wv, (float4*)wsum);

    // K2: Vsum = v_in @ W_sum + b_sum   (M=200, K=1536, N=256)
    vsum_gemm_kernel<<<200 / 8, 256, 0, stream>>>(feat, wsum, bv, vsum);

    // K3: fused attention per (b, sq)
    attn_kernel<<<BS * L, 256, 0, stream>>>(feat, query, vsum, outp);
}

// Round 2
// 93.583 us; speedup vs baseline: 2.0905x; 2.0905x over previous
//
#include <hip/hip_runtime.h>

// Problem constants (from reference)
#define N_CAM   6
#define N_REF   4
#define N_HEADS 8
#define EMBD    256
#define HS      32
#define L       100     // seq_len = 10*10
#define BS      2
#define CAM_STRIDE (L * EMBD)   // 25600 floats per (b, cam)
#define CK      (N_CAM * L)     // 600 combined (cam, sk) index

// Workspace layout (floats):
//   wsum : 1536*256            = 393216
//   ktr  : 2*8*32*600          = 307200   [b][h][d][cam*100+sk]
//   P    : 12*200*256          = 614400   GEMM split-K partials [chunk][row][e]
//   vsum : 200*256             = 51200
//   E    : 2*100*8*100         = 160000   [b][sq][h][sk]
#define WS_WSUM 0
#define WS_KTR  (WS_WSUM + 1536*256)
#define WS_P    (WS_KTR + 307200)
#define WS_VSUM (WS_P + 12*200*256)
#define WS_E    (WS_VSUM + 51200)

// ---------------------------------------------------------------------------
// Kernel A (480 blocks):
//  blocks [0,96):  transpose feat -> ktr[b][h][d][cam*100+sk]  (d-major K)
//  blocks [96,480): fold W_v (1536x1024) over 4 ref slots -> wsum (1536x256)
// ---------------------------------------------------------------------------
__global__ __launch_bounds__(256) void prep_kernel(const float* __restrict__ feat,
                                                   const float4* __restrict__ Wv4,
                                                   float* __restrict__ ws) {
    const int t = threadIdx.x;
    if (blockIdx.x < 96) {
        // ---- transpose branch: one block per (b, cam, h) ----
        __shared__ float tile[100][33];   // +1 pad: conflict-free column reads
        int blk = blockIdx.x;
        int b   = blk / 48;
        int rem = blk - b * 48;
        int cam = rem >> 3;
        int h   = rem & 7;
        const float* src = feat + (size_t)(b * N_CAM + cam) * CAM_STRIDE + h * HS;
        for (int idx = t; idx < 100 * 32; idx += 256) {
            int sk = idx >> 5;
            int d  = idx & 31;
            tile[sk][d] = src[sk * EMBD + d];          // 128B-contiguous runs
        }
        __syncthreads();
        float* ktr = ws + WS_KTR;
        for (int idx = t; idx < 100 * 32; idx += 256) {
            int d  = idx / 100;
            int sk = idx - d * 100;
            // lanes at fixed d write consecutive sk -> coalesced
            ktr[((size_t)(b * N_HEADS + h) * HS + d) * CK + cam * L + sk] = tile[sk][d];
        }
    } else {
        // ---- W fold branch: wsum[i][e] = sum_ref W_v[i][ref*256+e] ----
        int tid = (blockIdx.x - 96) * 256 + t;         // 0 .. 1536*64-1
        int i  = tid >> 6;
        int e4 = tid & 63;
        const float4* row = Wv4 + (size_t)i * 256;
        float4 a = row[e4];
        float4 b = row[64 + e4];
        float4 c = row[128 + e4];
        float4 d = row[192 + e4];
        float4 o;
        o.x = a.x + b.x + c.x + d.x;
        o.y = a.y + b.y + c.y + d.y;
        o.z = a.z + b.z + c.z + d.z;
        o.w = a.w + b.w + c.w + d.w;
        ((float4*)(ws + WS_WSUM))[(size_t)i * 64 + e4] = o;
    }
}

// ---------------------------------------------------------------------------
// Kernel B (600 blocks): Vsum GEMM split-K partials.
// block = (rg, c): rows rg*4..+4, K-chunk c (128 of 1536). M=200,N=256,K=1536.
// P[c][row][e] = sum_{kk in chunk} v_in[row][k0+kk] * wsum[k0+kk][e]
// ---------------------------------------------------------------------------
__global__ __launch_bounds__(256) void vsum_gemm_kernel(const float* __restrict__ feat,
                                                        const float* __restrict__ ws_in,
                                                        float* __restrict__ ws_out) {
    __shared__ float a_tile[4][128];
    const int t  = threadIdx.x;
    const int rg = blockIdx.x / 12;
    const int c  = blockIdx.x - rg * 12;
    const int r0 = rg * 4;
    const int k0 = c * 128;
    const int cam    = c >> 1;           // 128-chunks never cross a camera
    const int e2base = (c & 1) << 7;

    // stage A tile: a_tile[j][kk] = v_in[r0+j][cam*256 + e2base + kk]
    for (int idx = t; idx < 4 * 128; idx += 256) {
        int j  = idx >> 7;
        int kk = idx & 127;
        int row = r0 + j;
        int b = row >= 100;
        int s = row - b * 100;
        a_tile[j][kk] = feat[(size_t)(b * N_CAM + cam) * CAM_STRIDE + s * EMBD + e2base + kk];
    }
    __syncthreads();

    float acc[4] = {0.f, 0.f, 0.f, 0.f};
    const float* wp = ws_in + WS_WSUM + (size_t)k0 * 256 + t;
#pragma unroll 8
    for (int kk = 0; kk < 128; ++kk) {
        float w = wp[kk * 256];          // coalesced across t
#pragma unroll
        for (int j = 0; j < 4; ++j) acc[j] += a_tile[j][kk] * w;
    }

    float* P = ws_out + WS_P;
#pragma unroll
    for (int j = 0; j < 4; ++j)
        P[((size_t)c * 200 + r0 + j) * 256 + t] = acc[j];
}

// ---------------------------------------------------------------------------
// Kernel C (600 blocks):
//  blocks [0,200):  reduce partials -> vsum[row][e] (+ folded bias)
//  blocks [200,600): E-compute: block = (b, h, sq-tile of 4)
//    E[b][sq][h][sk] = sum_cam exp( dot_d(q[b,sq,h,d], ktr[b][h][d][cam*100+sk]) * scale )
// ---------------------------------------------------------------------------
__global__ __launch_bounds__(256) void mid_kernel(const float* __restrict__ query,
                                                  const float* __restrict__ b_v,
                                                  float* __restrict__ ws) {
    const int t = threadIdx.x;
    if (blockIdx.x < 200) {
        // ---- reduce branch ----
        const int row = blockIdx.x;
        const float* P = ws + WS_P;
        float acc = b_v[t] + b_v[256 + t] + b_v[512 + t] + b_v[768 + t];
#pragma unroll
        for (int c = 0; c < 12; ++c)
            acc += P[((size_t)c * 200 + row) * 256 + t];
        ws[WS_VSUM + (size_t)row * 256 + t] = acc;
    } else {
        // ---- E branch ----
        __shared__ float q_s[4][32];
        __shared__ float es[4][CK];      // exp(scores) for 4 sq x 600 (cam,sk)
        int idx = blockIdx.x - 200;      // [0,400)
        int b   = idx / 200;
        int rem = idx - b * 200;
        int h   = rem / 25;
        int sqt = rem - h * 25;
        int sq0 = sqt * 4;

        if (t < 128) {
            int sqj = t >> 5;
            int d   = t & 31;
            q_s[sqj][d] = query[(size_t)(b * L + sq0 + sqj) * EMBD + h * HS + d];
        }
        __syncthreads();

        const float scale = 0.17677669529663687f;  // 1/sqrt(32)
        const float* kt = ws + WS_KTR + (size_t)(b * N_HEADS + h) * HS * CK;

        // each thread: up to 3 ck columns, 4 sq accumulators each
#pragma unroll
        for (int i = 0; i < 3; ++i) {
            int ck = t + i * 256;
            if (ck < CK) {
                float acc0 = 0.f, acc1 = 0.f, acc2 = 0.f, acc3 = 0.f;
#pragma unroll 8
                for (int d = 0; d < 32; ++d) {
                    float k = kt[(size_t)d * CK + ck];   // coalesced across lanes
                    acc0 += q_s[0][d] * k;
                    acc1 += q_s[1][d] * k;
                    acc2 += q_s[2][d] * k;
                    acc3 += q_s[3][d] * k;
                }
                es[0][ck] = __expf(acc0 * scale);
                es[1][ck] = __expf(acc1 * scale);
                es[2][ck] = __expf(acc2 * scale);
                es[3][ck] = __expf(acc3 * scale);
            }
        }
        __syncthreads();

        // fold cameras: E[sq][sk] = sum_cam es[sq][cam*100+sk]
        float* E = ws + WS_E;
        for (int p = t; p < 4 * L; p += 256) {
            int sqj = p / 100;
            int sk  = p - sqj * 100;
            float e = 0.f;
#pragma unroll
            for (int cam = 0; cam < N_CAM; ++cam)
                e += es[sqj][cam * L + sk];
            E[((size_t)(b * L + sq0 + sqj) * N_HEADS + h) * L + sk] = e;
        }
    }
}

// ---------------------------------------------------------------------------
// Kernel D (200 blocks): out[b,sq,e] = sum_sk E[b,sq,h,sk]*vsum[b*100+sk][e]
//                                      / (4 * sum_sk E[b,sq,h,sk])
// ---------------------------------------------------------------------------
__global__ __launch_bounds__(256) void out_kernel(const float* __restrict__ ws,
                                                  float* __restrict__ out) {
    const int t  = threadIdx.x;
    const int b  = blockIdx.x / 100;
    const int sq = blockIdx.x - b * 100;
    const int h  = t >> 5;

    const float* Eh = ws + WS_E + ((size_t)(b * L + sq) * N_HEADS + h) * L;
    const float* vb = ws + WS_VSUM + (size_t)b * L * EMBD + t;

    float acc = 0.f, sumE = 0.f;
#pragma unroll 4
    for (int sk = 0; sk < L; ++sk) {
        float e = Eh[sk];                 // broadcast within 32-lane head group
        acc  += e * vb[sk * EMBD];        // coalesced
        sumE += e;
    }
    out[(size_t)(b * L + sq) * EMBD + t] = acc * (0.25f / sumE);
}

// ---------------------------------------------------------------------------
extern "C" void kernel_launch(void* const* d_in, const int* in_sizes, int n_in,
                              void* d_out, int out_size, void* d_ws, size_t ws_size,
                              hipStream_t stream) {
    const float* feat  = (const float*)d_in[0];  // (2,1,6,256,10,10)
    const float* query = (const float*)d_in[1];  // (2,100,256)
    const float* Wv    = (const float*)d_in[2];  // (1536,1024)
    const float* bv    = (const float*)d_in[3];  // (1024,)
    float* outp = (float*)d_out;                 // (2,100,256)
    float* ws   = (float*)d_ws;

    // A: feat transpose (d-major K) + W_v column fold
    prep_kernel<<<480, 256, 0, stream>>>(feat, (const float4*)Wv, ws);

    // B: Vsum GEMM split-K partials (M=200, N=256, K=1536; 12 chunks)
    vsum_gemm_kernel<<<600, 256, 0, stream>>>(feat, ws, ws);

    // C: partial reduce -> vsum  |  scores+exp+cam-fold -> E
    mid_kernel<<<600, 256, 0, stream>>>(query, bv, ws);

    // D: weighted sum + normalization
    out_kernel<<<200, 256, 0, stream>>>(ws, outp);
}